// Round 18
// baseline (272.195 us; speedup 1.0000x reference)
//
#include <hip/hip_runtime.h>
#include <cmath>

namespace {

constexpr int S = 2048, B = 2, D = 1024, H = 16, E = 64;
constexpr int RM = S * B;
constexpr int K = D;
constexpr int KVB = 64;
constexpr int SEGS_PER_HM = 48;   // t=0:2 segs, t=1..16:1, t=17..31:2

// exp2-domain constants: score2 = raw*(0.125*log2e) - km*KMB2 - causal*KMB2
constexpr float QSCL = 0.18033688011112043f;      // 0.125 * log2(e)
constexpr float KMB2 = 1.4426950408889634e18f;    // 1e18 * log2(e)

using s16x8 = __attribute__((ext_vector_type(8))) short;
using u16x8 = __attribute__((ext_vector_type(8))) unsigned short;
using f32x4 = __attribute__((ext_vector_type(4))) float;
using u32x2 = __attribute__((ext_vector_type(2))) unsigned;
using u32x4 = __attribute__((ext_vector_type(4))) unsigned;
typedef unsigned short ushort;
typedef unsigned int u32;

// LPT order: longest segments first (static; assumes worst-case seg lengths)
__constant__ unsigned char SEG_ORDER[48] = {
    17,0,1,16,44,46,47,15,40,42,43,45,14,36,38,39,41,13,32,34,35,37,
    12,28,30,31,33,11,24,26,27,29,10,20,22,23,25,9,18,19,21,8,7,6,5,4,3,2};

__device__ inline f32x4 mfma16(s16x8 a, s16x8 b, f32x4 c) {
    return __builtin_amdgcn_mfma_f32_16x16x32_bf16(a, b, c, 0, 0, 0);
}

__device__ inline ushort f2bf(float f) {
    unsigned u = __builtin_bit_cast(unsigned, f);
    u += 0x7fffu + ((u >> 16) & 1u);          // RNE
    return (ushort)(u >> 16);
}

__device__ inline u32 cvtpk_bf16(float lo, float hi) {
    u32 r;
    asm("v_cvt_pk_bf16_f32 %0, %1, %2" : "=v"(r) : "v"(lo), "v"(hi));
    return r;
}

__device__ inline float fexp2(float x) {
#if __has_builtin(__builtin_amdgcn_exp2f)
    return __builtin_amdgcn_exp2f(x);
#else
    return exp2f(x);
#endif
}

__device__ inline void gload_lds16(const void* g, void* l) {
    __builtin_amdgcn_global_load_lds(
        (const __attribute__((address_space(1))) u32*)g,
        (__attribute__((address_space(3))) u32*)l,
        16, 0, 0);
}

// ---------------------------------------------------------------------------
// fp32 -> bf16 converter (weights only — activations fused into proj)
// ---------------------------------------------------------------------------
__global__ __launch_bounds__(256)
void cvt4_kernel(const float* __restrict__ a, const float* __restrict__ b,
                 const float* __restrict__ c, const float* __restrict__ d,
                 ushort* __restrict__ ao, ushort* __restrict__ bo2,
                 ushort* __restrict__ co, ushort* __restrict__ dd)
{
    const float* src = (blockIdx.y == 0) ? a : (blockIdx.y == 1) ? b : (blockIdx.y == 2) ? c : d;
    ushort* dst      = (blockIdx.y == 0) ? ao : (blockIdx.y == 1) ? bo2 : (blockIdx.y == 2) ? co : dd;
    const size_t i = ((size_t)blockIdx.x * 256 + threadIdx.x) * 8;
    float4 x = *reinterpret_cast<const float4*>(&src[i]);
    float4 y = *reinterpret_cast<const float4*>(&src[i + 4]);
    u16x8 o;
    o[0]=f2bf(x.x); o[1]=f2bf(x.y); o[2]=f2bf(x.z); o[3]=f2bf(x.w);
    o[4]=f2bf(y.x); o[5]=f2bf(y.y); o[6]=f2bf(y.z); o[7]=f2bf(y.w);
    *reinterpret_cast<u16x8*>(&dst[i]) = o;
}

// ---------------------------------------------------------------------------
// MFMA GEMM core, 128x128 tile, 8 waves (512 thr), single-buffered (m97
// 2-barrier structure). bf16-A variant (out_gemm) — byte-identical to R16.
// ---------------------------------------------------------------------------
__device__ inline void mm_core2(const ushort* __restrict__ A, const ushort* __restrict__ W,
                                ushort* Albuf, ushort* Blbuf, int r0, int n0,
                                f32x4 (&acc)[4][2])
{
    const int t  = threadIdx.x;
    const int w  = t >> 6, l = t & 63;
    const int lr = l & 15, lg = l >> 4;
    const int wr = w >> 2, wc = w & 3;       // 2x4 grid of 64x32 quadrants
    const int srow = t >> 3;                 // 0..63
    const int gch  = (t & 7) ^ (srow & 7);

    for (int kt = 0; kt < K; kt += 64) {
        __syncthreads();
        #pragma unroll
        for (int c = 0; c < 2; ++c) {
            gload_lds16(&A[(size_t)(r0 + c * 64 + srow) * K + kt + gch * 8],
                        (char*)Albuf + c * 8192 + t * 16);
            gload_lds16(&W[(size_t)(n0 + c * 64 + srow) * K + kt + gch * 8],
                        (char*)Blbuf + c * 8192 + t * 16);
        }
        __syncthreads();

        #pragma unroll
        for (int ks = 0; ks < 2; ++ks) {
            s16x8 af[4], bf[2];
            #pragma unroll
            for (int mf = 0; mf < 4; ++mf) {
                const int row = wr * 64 + mf * 16 + lr;
                const int ch  = (ks * 4 + lg) ^ (row & 7);
                af[mf] = *reinterpret_cast<const s16x8*>((const char*)Albuf + row * 128 + ch * 16);
            }
            #pragma unroll
            for (int nf = 0; nf < 2; ++nf) {
                const int row = wc * 32 + nf * 16 + lr;
                const int ch  = (ks * 4 + lg) ^ (row & 7);
                bf[nf] = *reinterpret_cast<const s16x8*>((const char*)Blbuf + row * 128 + ch * 16);
            }
            #pragma unroll
            for (int mf = 0; mf < 4; ++mf)
                #pragma unroll
                for (int nf = 0; nf < 2; ++nf)
                    acc[mf][nf] = mfma16(af[mf], bf[nf], acc[mf][nf]);
        }
    }
}

// ---------------------------------------------------------------------------
// fp32-A variant (proj), R18: NO LDS for A. Each lane loads its A-fragment
// directly from global fp32 (L2-resident: same data re-read by 4 same-wr
// waves/block and 8 n-panel blocks) and converts in-register via cvt_pk.
// Loads live inside the MFMA phase -> compiler-counted waitcnts + TLP hide
// L2 latency; the barrier drain hits already-consumed loads. W keeps the
// proven global_load_lds path (16 KB LDS only).
// ---------------------------------------------------------------------------
__device__ inline void mm_core2_f32A(const float* __restrict__ A, const ushort* __restrict__ W,
                                     ushort* Blbuf, int r0, int n0,
                                     f32x4 (&acc)[4][2])
{
    const int t  = threadIdx.x;
    const int w  = t >> 6, l = t & 63;
    const int lr = l & 15, lg = l >> 4;
    const int wr = w >> 2, wc = w & 3;
    const int srow = t >> 3;                 // 0..63 (W staging rows)
    const int gch  = (t & 7) ^ (srow & 7);

    // per-mf A row base (fp32); fragment cols = kt + ks*32 + lg*8 .. +8
    const float* arow0 = &A[(size_t)(r0 + wr * 64 +  0 + lr) * K + lg * 8];
    const float* arow1 = &A[(size_t)(r0 + wr * 64 + 16 + lr) * K + lg * 8];
    const float* arow2 = &A[(size_t)(r0 + wr * 64 + 32 + lr) * K + lg * 8];
    const float* arow3 = &A[(size_t)(r0 + wr * 64 + 48 + lr) * K + lg * 8];

    for (int kt = 0; kt < K; kt += 64) {
        __syncthreads();                     // prev K-step's W readers done
        #pragma unroll
        for (int c = 0; c < 2; ++c)
            gload_lds16(&W[(size_t)(n0 + c * 64 + srow) * K + kt + gch * 8],
                        (char*)Blbuf + c * 8192 + t * 16);
        __syncthreads();                     // W visible

        #pragma unroll
        for (int ks = 0; ks < 2; ++ks) {
            s16x8 bf[2];
            #pragma unroll
            for (int nf = 0; nf < 2; ++nf) {
                const int row = wc * 32 + nf * 16 + lr;
                const int ch  = (ks * 4 + lg) ^ (row & 7);
                bf[nf] = *reinterpret_cast<const s16x8*>((const char*)Blbuf + row * 128 + ch * 16);
            }
            const int co = kt + ks * 32;
            #pragma unroll
            for (int mf = 0; mf < 4; ++mf) {
                const float* ap = (mf == 0) ? arow0 : (mf == 1) ? arow1
                                : (mf == 2) ? arow2 : arow3;
                const float4 x = *reinterpret_cast<const float4*>(ap + co);
                const float4 y = *reinterpret_cast<const float4*>(ap + co + 4);
                u32x4 q = {cvtpk_bf16(x.x, x.y), cvtpk_bf16(x.z, x.w),
                           cvtpk_bf16(y.x, y.y), cvtpk_bf16(y.z, y.w)};
                const s16x8 af = __builtin_bit_cast(s16x8, q);
                acc[mf][0] = mfma16(af, bf[0], acc[mf][0]);
                acc[mf][1] = mfma16(af, bf[1], acc[mf][1]);
            }
        }
    }
}

__global__ __launch_bounds__(512)
void proj_gemm(const float* __restrict__ qa, const float* __restrict__ ka,
               const float* __restrict__ va,
               const ushort* __restrict__ wq, const ushort* __restrict__ wk,
               const ushort* __restrict__ wv,
               const float* __restrict__ bq, const float* __restrict__ bk,
               const float* __restrict__ bv,
               ushort* __restrict__ qd, ushort* __restrict__ kd, ushort* __restrict__ vtd)
{
    __shared__ ushort Blbuf[128 * 64];
    const int z = blockIdx.z;
    const float*  A    = (z == 0) ? qa : (z == 1) ? ka : va;
    const ushort* W    = (z == 0) ? wq : (z == 1) ? wk : wv;
    const float*  bias = (z == 0) ? bq : (z == 1) ? bk : bv;
    const int r0 = blockIdx.x * 128, n0 = blockIdx.y * 128;

    f32x4 acc[4][2] = {};
    mm_core2_f32A(A, W, Blbuf, r0, n0, acc);

    const int t = threadIdx.x, w = t >> 6, l = t & 63, lr = l & 15, lg = l >> 4;
    const int wr = w >> 2, wc = w & 3;
    #pragma unroll
    for (int mf = 0; mf < 4; ++mf) {
        #pragma unroll
        for (int nf2 = 0; nf2 < 2; ++nf2) {
            const int n = n0 + wc * 32 + nf2 * 16 + lr;
            const int h = n >> 6, e = n & 63;
            const float bb = bias[n];
            #pragma unroll
            for (int rg = 0; rg < 4; ++rg) {
                const int r = r0 + wr * 64 + mf * 16 + lg * 4 + rg;
                const int i = r >> 1, m = r & 1;
                const ushort val = f2bf(acc[mf][nf2][rg] + bb);
                if (z < 2) {
                    ushort* dst = (z == 0) ? qd : kd;
                    dst[(((size_t)(h * B + m)) * S + i) * E + e] = val;
                } else {
                    vtd[(((size_t)(h * B + m)) * E + e) * S + i] = val;
                }
            }
        }
    }
}

__global__ __launch_bounds__(512)
void out_gemm(const ushort* __restrict__ A, const ushort* __restrict__ W,
              const float* __restrict__ bias, float* __restrict__ Cout)
{
    __shared__ ushort Albuf[128 * 64];
    __shared__ ushort Blbuf[128 * 64];
    const int r0 = blockIdx.x * 128, n0 = blockIdx.y * 128;

    f32x4 acc[4][2] = {};
    mm_core2(A, W, Albuf, Blbuf, r0, n0, acc);

    const int t = threadIdx.x, w = t >> 6, l = t & 63, lr = l & 15, lg = l >> 4;
    const int wr = w >> 2, wc = w & 3;
    #pragma unroll
    for (int mf = 0; mf < 4; ++mf) {
        #pragma unroll
        for (int nf2 = 0; nf2 < 2; ++nf2) {
            const int n = n0 + wc * 32 + nf2 * 16 + lr;
            const float bb = bias[n];
            #pragma unroll
            for (int rg = 0; rg < 4; ++rg) {
                const int r = r0 + wr * 64 + mf * 16 + lg * 4 + rg;
                Cout[(size_t)r * D + n] = acc[mf][nf2][rg] + bb;
            }
        }
    }
}

// ---------------------------------------------------------------------------
// prescan: fu[m] = min{j : key_mask[j,m]==0} (else S); kmf = mask * KMB2
// ---------------------------------------------------------------------------
__global__ __launch_bounds__(256)
void prescan_kernel(const int* __restrict__ km, int* __restrict__ fu,
                    float* __restrict__ kmf)
{
    __shared__ int red[256];
    const int m = blockIdx.x, t = threadIdx.x;
    int best = S;
    for (int j = t; j < S; j += 256) {
        const int v = km[(size_t)j * B + m];
        kmf[(size_t)m * S + j] = v ? KMB2 : 0.0f;
        if (v == 0) best = min(best, j);
    }
    red[t] = best;
    __syncthreads();
    for (int s = 128; s > 0; s >>= 1) {
        if (t < s) red[t] = min(red[t], red[t + s]);
        __syncthreads();
    }
    if (t == 0) fu[m] = red[0];
}

__device__ inline int nseg_of(int t)  { return (t == 0 || t >= 17) ? 2 : 1; }
__device__ inline int segoff_of(int t){ return (t == 0) ? 0 : (t <= 16 ? t + 1 : 2 * t - 16); }

// ---------------------------------------------------------------------------
// Balanced MFMA flash attention — BYTE-IDENTICAL to R15/R16 (proven).
// ---------------------------------------------------------------------------
__global__ __launch_bounds__(256)
void attn_seg(const ushort* __restrict__ q, const ushort* __restrict__ k,
              const ushort* __restrict__ vt, const int* __restrict__ fu,
              const float* __restrict__ kmf,
              float* __restrict__ part_O, float* __restrict__ part_ml,
              ushort* __restrict__ a_ws)
{
    // T1 remap: 1536 blocks = 8 XCDs x 192; XCD c gets hm in [4c, 4c+4)
    const int lin = blockIdx.x + SEGS_PER_HM * (blockIdx.y + B * blockIdx.z);
    const int nf  = (lin & 7) * 192 + (lin >> 3);
    const int s   = SEG_ORDER[nf % SEGS_PER_HM];
    const int m   = (nf / SEGS_PER_HM) % B;
    const int h   = nf / (SEGS_PER_HM * B);
    int t, kk;
    if (s < 2)       { t = 0;               kk = s; }
    else if (s < 18) { t = s - 1;           kk = 0; }
    else             { t = 17 + ((s - 18) >> 1); kk = (s - 18) & 1; }
    const int i0 = t * 64;
    const int hm = h * B + m;
    const int seg = hm * SEGS_PER_HM + s;

    const int ns = nseg_of(t);
    const int h1 = (t == 0) ? 16 : ((t + 2) >> 1);
    const int jendT = (fu[m] <= i0) ? (t + 1) : 32;
    const int lo = (ns == 2 && kk == 1) ? h1 : 0;
    const int hi = (ns == 2 && kk == 0) ? min(h1, jendT) : jendT;

    const ushort* Qb  = q  + (size_t)hm * S * E;
    const ushort* Kb  = k  + (size_t)hm * S * E;
    const ushort* Vtb = vt + (size_t)hm * E * S;
    const float*  kmfm = kmf + (size_t)m * S;

    __shared__ ushort Ks[2][KVB * 64];
    __shared__ ushort Vts[2][E * 64];
    __shared__ ushort Pw[4][16 * 64];

    const int tid = threadIdx.x;
    const int wv  = tid >> 6;
    const int l   = tid & 63;
    const int lg  = l >> 4;
    const int lcc = l & 15;
    const int a7  = lcc & 7;
    const int gi  = i0 + wv * 16 + lcc;

    const int srow = tid >> 3;
    const int sch  = (tid & 7) ^ (srow & 7);

    s16x8 qf0, qf1;
    {
        const ushort* qp = &Qb[(size_t)gi * E + lg * 8];
        qf0 = *reinterpret_cast<const s16x8*>(qp);
        qf1 = *reinterpret_cast<const s16x8*>(qp + 32);
    }

    float m_run = -INFINITY, l_run = 0.0f;
    f32x4 oacc[4] = {};

    auto STAGE = [&](int buf, int tj) {
        const int j0 = tj * 64;
        gload_lds16(&Kb[(size_t)(j0 + srow) * E + sch * 8],
                    (char*)&Ks[buf][0] + tid * 16);
        gload_lds16(&Kb[(size_t)(j0 + 32 + srow) * E + sch * 8],
                    (char*)&Ks[buf][0] + 4096 + tid * 16);
        gload_lds16(&Vtb[(size_t)srow * S + j0 + sch * 8],
                    (char*)&Vts[buf][0] + tid * 16);
        gload_lds16(&Vtb[(size_t)(32 + srow) * S + j0 + sch * 8],
                    (char*)&Vts[buf][0] + 4096 + tid * 16);
    };

    STAGE(0, lo);
    __syncthreads();
    int cur = 0;

    for (int tj = lo; tj < hi; ++tj) {
        const int j0 = tj * 64;
        if (tj + 1 < hi) STAGE(cur ^ 1, tj + 1);

        float4 km4[4];
        #pragma unroll
        for (int jt = 0; jt < 4; ++jt)
            km4[jt] = *reinterpret_cast<const float4*>(&kmfm[j0 + jt * 16 + lg * 4]);

        // ---- S^T = K . Q^T  (T5 boost)
        f32x4 sacc[4];
        __builtin_amdgcn_s_setprio(1);
        #pragma unroll
        for (int jt = 0; jt < 4; ++jt) {
            const char* kb = (const char*)&Ks[cur][0] + (jt * 16 + lcc) * 128;
            s16x8 kf0 = *reinterpret_cast<const s16x8*>(kb + (lg ^ a7) * 16);
            s16x8 kf1 = *reinterpret_cast<const s16x8*>(kb + ((lg ^ a7) ^ 4) * 16);
            f32x4 a = {};
            a = mfma16(kf0, qf0, a);
            a = mfma16(kf1, qf1, a);
            sacc[jt] = a;
        }
        __builtin_amdgcn_s_setprio(0);

        // ---- scale + masks in exp2 domain
        if (j0 >= i0) {
            #pragma unroll
            for (int jt = 0; jt < 4; ++jt) {
                const int jmi = j0 + jt * 16 + lg * 4 - gi;
                #pragma unroll
                for (int r = 0; r < 4; ++r) {
                    float sc = fmaf(sacc[jt][r], QSCL, -((const float*)&km4[jt])[r]);
                    sc -= (jmi + r > 0) ? KMB2 : 0.0f;
                    sacc[jt][r] = sc;
                }
            }
        } else {
            #pragma unroll
            for (int jt = 0; jt < 4; ++jt)
                #pragma unroll
                for (int r = 0; r < 4; ++r)
                    sacc[jt][r] = fmaf(sacc[jt][r], QSCL, -((const float*)&km4[jt])[r]);
        }

        // ---- online softmax, defer-rescale
        float mm = -INFINITY;
        #pragma unroll
        for (int jt = 0; jt < 4; ++jt)
            #pragma unroll
            for (int r = 0; r < 4; ++r) mm = fmaxf(mm, sacc[jt][r]);
        mm = fmaxf(mm, __shfl_xor(mm, 16));
        mm = fmaxf(mm, __shfl_xor(mm, 32));

        if (!__all(mm <= m_run)) {
            const float m_new = fmaxf(m_run, mm);
            const float scale = fexp2(m_run - m_new);
            m_run = m_new;
            l_run *= scale;
            float scr[4];
            #pragma unroll
            for (int r = 0; r < 4; ++r)
                scr[r] = __shfl(scale, (l & 48) | (lg * 4 + r));
            #pragma unroll
            for (int et = 0; et < 4; ++et)
                #pragma unroll
                for (int r = 0; r < 4; ++r) oacc[et][r] *= scr[r];
        }

        float psum = 0.0f;
        #pragma unroll
        for (int jt = 0; jt < 4; ++jt) {
            const float p0 = fexp2(sacc[jt][0] - m_run);
            const float p1 = fexp2(sacc[jt][1] - m_run);
            const float p2 = fexp2(sacc[jt][2] - m_run);
            const float p3 = fexp2(sacc[jt][3] - m_run);
            psum += (p0 + p1) + (p2 + p3);
            const u32 w0 = cvtpk_bf16(p0, p1);
            const u32 w1 = cvtpk_bf16(p2, p3);
            const int pby = lcc * 128 + (((jt * 2 + (lg >> 1)) ^ a7) << 4) + ((lg & 1) << 3);
            *reinterpret_cast<u32x2*>((char*)&Pw[wv][0] + pby) = (u32x2){w0, w1};
        }
        psum += __shfl_xor(psum, 16);
        psum += __shfl_xor(psum, 32);
        l_run += psum;

        // ---- PV: A = P (per-wave LDS), B = V^T  (T5 boost)
        {
            const char* pb = (const char*)&Pw[wv][0] + lcc * 128;
            __builtin_amdgcn_s_setprio(1);
            s16x8 pf0 = *reinterpret_cast<const s16x8*>(pb + (lg ^ a7) * 16);
            s16x8 pf1 = *reinterpret_cast<const s16x8*>(pb + ((lg ^ a7) ^ 4) * 16);
            #pragma unroll
            for (int et = 0; et < 4; ++et) {
                const char* vb = (const char*)&Vts[cur][0] + (et * 16 + lcc) * 128;
                s16x8 vf0 = *reinterpret_cast<const s16x8*>(vb + (lg ^ a7) * 16);
                s16x8 vf1 = *reinterpret_cast<const s16x8*>(vb + ((lg ^ a7) ^ 4) * 16);
                oacc[et] = mfma16(pf0, vf0, oacc[et]);
                oacc[et] = mfma16(pf1, vf1, oacc[et]);
            }
            __builtin_amdgcn_s_setprio(0);
        }

        __syncthreads();
        cur ^= 1;
    }

    if (ns == 1) {
        // single segment: normalize and emit bf16 directly
        const float inv = 1.0f / l_run;
        float linv4[4];
        #pragma unroll
        for (int r = 0; r < 4; ++r)
            linv4[r] = __shfl(inv, (l & 48) | (lg * 4 + r));
        #pragma unroll
        for (int et = 0; et < 4; ++et) {
            #pragma unroll
            for (int r = 0; r < 4; ++r) {
                const int gi2 = i0 + wv * 16 + lg * 4 + r;
                a_ws[((size_t)gi2 * B + m) * D + h * E + et * 16 + lcc] =
                    f2bf(oacc[et][r] * linv4[r]);
            }
        }
    } else {
        #pragma unroll
        for (int et = 0; et < 4; ++et)
            #pragma unroll
            for (int r = 0; r < 4; ++r)
                part_O[((size_t)seg * 64 + wv * 16 + lg * 4 + r) * 64 + et * 16 + lcc] = oacc[et][r];
        if (lg == 0) {
            part_ml[((size_t)seg * 64 + wv * 16 + lcc) * 2]     = m_run;
            part_ml[((size_t)seg * 64 + wv * 16 + lcc) * 2 + 1] = l_run;
        }
    }
}

// ---------------------------------------------------------------------------
// combine: merge the 2-segment q-tiles only (t=0, 17..31)
// ---------------------------------------------------------------------------
__global__ __launch_bounds__(256)
void attn_combine(const float* __restrict__ part_O, const float* __restrict__ part_ml,
                  ushort* __restrict__ a_ws)
{
    const int t = (blockIdx.x == 0) ? 0 : (16 + blockIdx.x);   // 0, 17..31
    const int m = blockIdx.y, h = blockIdx.z;
    const int hm = h * B + m;
    const int seg0 = hm * SEGS_PER_HM + segoff_of(t);

    const int tid = threadIdx.x;
    const int row = tid >> 2;
    const int e0  = (tid & 3) * 16;
    const int gi  = t * 64 + row;

    const size_t r0 = (size_t)seg0 * 64 + row;
    const size_t r1 = ((size_t)(seg0 + 1)) * 64 + row;
    const float m0 = part_ml[r0 * 2], l0 = part_ml[r0 * 2 + 1];
    const float m1 = part_ml[r1 * 2], l1 = part_ml[r1 * 2 + 1];
    const float ms = fmaxf(m0, m1);
    const float w0 = fexp2(m0 - ms);
    const float w1 = fexp2(m1 - ms);
    const float linv = 1.0f / (l0 * w0 + l1 * w1);

    ushort* dst = a_ws + ((size_t)gi * B + m) * D + h * E + e0;
    #pragma unroll
    for (int c = 0; c < 4; ++c) {
        float4 o0 = *reinterpret_cast<const float4*>(&part_O[r0 * 64 + e0 + c * 4]);
        float4 o1 = *reinterpret_cast<const float4*>(&part_O[r1 * 64 + e0 + c * 4]);
        float ov[4];
        ov[0] = o0.x * w0 + o1.x * w1;
        ov[1] = o0.y * w0 + o1.y * w1;
        ov[2] = o0.z * w0 + o1.z * w1;
        ov[3] = o0.w * w0 + o1.w * w1;
        dst[c * 4 + 0] = f2bf(ov[0] * linv);
        dst[c * 4 + 1] = f2bf(ov[1] * linv);
        dst[c * 4 + 2] = f2bf(ov[2] * linv);
        dst[c * 4 + 3] = f2bf(ov[3] * linv);
    }
}

} // anonymous namespace

extern "C" void kernel_launch(void* const* d_in, const int* in_sizes, int n_in,
                              void* d_out, int out_size, void* d_ws, size_t ws_size,
                              hipStream_t stream)
{
    const float* query = (const float*)d_in[0];
    const float* key   = (const float*)d_in[1];
    const float* value = (const float*)d_in[2];
    const int*   kmask = (const int*)  d_in[3];
    const float* Wq    = (const float*)d_in[4];
    const float* bq    = (const float*)d_in[5];
    const float* Wk    = (const float*)d_in[6];
    const float* bk    = (const float*)d_in[7];
    const float* Wv    = (const float*)d_in[8];
    const float* bv    = (const float*)d_in[9];
    const float* Wo    = (const float*)d_in[10];
    const float* bo    = (const float*)d_in[11];
    float* out = (float*)d_out;

    const size_t act = (size_t)RM * D;
    const size_t wsz = (size_t)D * D;
    ushort* wob  = (ushort*)d_ws;
    ushort* wqb  = wob + wsz;
    ushort* wkb  = wqb + wsz;
    ushort* wvb  = wkb + wsz;
    ushort* qa   = wvb + wsz;              // region unused by GEMMs;
    ushort* ka   = qa + act;               // reused for attn partials only
    ushort* va   = ka + act;
    ushort* q_ws = va + act;
    ushort* k_ws = q_ws + act;
    ushort* vt_ws= k_ws + act;
    ushort* a_ws = vt_ws + act;
    float* part_O  = (float*)qa;           // 1536*64*64 f32 == 3*act ushorts
    float* part_ml = (float*)wqb;          // 786 KB < 2 MB
    int*   fu      = (int*)wkb;            // 16 B
    float* kmf     = (float*)wkb + 8;      // S*B f32 = 16 KB < 2 MB

    cvt4_kernel<<<dim3(wsz / 8 / 256, 4), 256, 0, stream>>>(Wq, Wk, Wv, Wo, wqb, wkb, wvb, wob);

    proj_gemm<<<dim3(RM / 128, D / 128, 3), 512, 0, stream>>>(
        query, key, value, wqb, wkb, wvb, bq, bk, bv, q_ws, k_ws, vt_ws);

    prescan_kernel<<<dim3(B), 256, 0, stream>>>(kmask, fu, kmf);

    attn_seg<<<dim3(SEGS_PER_HM, B, H), 256, 0, stream>>>(
        q_ws, k_ws, vt_ws, fu, kmf, part_O, part_ml, a_ws);

    attn_combine<<<dim3(16, B, H), 256, 0, stream>>>(part_O, part_ml, a_ws);

    out_gemm<<<dim3(RM / 128, D / 128), 512, 0, stream>>>(a_ws, wob, bo, out);
}

// Round 19
// 132.383 us; speedup vs baseline: 2.0561x; 2.0561x over previous
//
#include <hip/hip_runtime.h>
#include <cmath>

namespace {

constexpr int S = 2048, B = 2, D = 1024, H = 16, E = 64;
constexpr int RM = S * B;
constexpr int K = D;
constexpr int KVB = 64;
constexpr int SEGS_PER_HM = 48;   // t=0:2 segs, t=1..16:1, t=17..31:2

// exp2-domain constants: score2 = raw*(0.125*log2e) - km*KMB2 - causal*KMB2
constexpr float QSCL = 0.18033688011112043f;      // 0.125 * log2(e)
constexpr float KMB2 = 1.4426950408889634e18f;    // 1e18 * log2(e)

using s16x8 = __attribute__((ext_vector_type(8))) short;
using u16x8 = __attribute__((ext_vector_type(8))) unsigned short;
using f32x4 = __attribute__((ext_vector_type(4))) float;
using u32x2 = __attribute__((ext_vector_type(2))) unsigned;
using u32x4 = __attribute__((ext_vector_type(4))) unsigned;
typedef unsigned short ushort;
typedef unsigned int u32;

// LPT order: longest segments first (static; assumes worst-case seg lengths)
__constant__ unsigned char SEG_ORDER[48] = {
    17,0,1,16,44,46,47,15,40,42,43,45,14,36,38,39,41,13,32,34,35,37,
    12,28,30,31,33,11,24,26,27,29,10,20,22,23,25,9,18,19,21,8,7,6,5,4,3,2};

__device__ inline f32x4 mfma16(s16x8 a, s16x8 b, f32x4 c) {
    return __builtin_amdgcn_mfma_f32_16x16x32_bf16(a, b, c, 0, 0, 0);
}

__device__ inline ushort f2bf(float f) {
    unsigned u = __builtin_bit_cast(unsigned, f);
    u += 0x7fffu + ((u >> 16) & 1u);          // RNE
    return (ushort)(u >> 16);
}

__device__ inline u32 cvtpk_bf16(float lo, float hi) {
    u32 r;
    asm("v_cvt_pk_bf16_f32 %0, %1, %2" : "=v"(r) : "v"(lo), "v"(hi));
    return r;
}

__device__ inline float fexp2(float x) {
#if __has_builtin(__builtin_amdgcn_exp2f)
    return __builtin_amdgcn_exp2f(x);
#else
    return exp2f(x);
#endif
}

__device__ inline void gload_lds16(const void* g, void* l) {
    __builtin_amdgcn_global_load_lds(
        (const __attribute__((address_space(1))) u32*)g,
        (__attribute__((address_space(3))) u32*)l,
        16, 0, 0);
}

// ---------------------------------------------------------------------------
// fp32 -> bf16 converter (weights only — activations fused into proj)
// ---------------------------------------------------------------------------
__global__ __launch_bounds__(256)
void cvt4_kernel(const float* __restrict__ a, const float* __restrict__ b,
                 const float* __restrict__ c, const float* __restrict__ d,
                 ushort* __restrict__ ao, ushort* __restrict__ bo2,
                 ushort* __restrict__ co, ushort* __restrict__ dd)
{
    const float* src = (blockIdx.y == 0) ? a : (blockIdx.y == 1) ? b : (blockIdx.y == 2) ? c : d;
    ushort* dst      = (blockIdx.y == 0) ? ao : (blockIdx.y == 1) ? bo2 : (blockIdx.y == 2) ? co : dd;
    const size_t i = ((size_t)blockIdx.x * 256 + threadIdx.x) * 8;
    float4 x = *reinterpret_cast<const float4*>(&src[i]);
    float4 y = *reinterpret_cast<const float4*>(&src[i + 4]);
    u16x8 o;
    o[0]=f2bf(x.x); o[1]=f2bf(x.y); o[2]=f2bf(x.z); o[3]=f2bf(x.w);
    o[4]=f2bf(y.x); o[5]=f2bf(y.y); o[6]=f2bf(y.z); o[7]=f2bf(y.w);
    *reinterpret_cast<u16x8*>(&dst[i]) = o;
}

// ---------------------------------------------------------------------------
// MFMA GEMM core, 128x128 tile, 8 waves (512 thr), single-buffered (m97
// 2-barrier structure). bf16-A variant (out_gemm).
// ---------------------------------------------------------------------------
__device__ inline void mm_core2(const ushort* __restrict__ A, const ushort* __restrict__ W,
                                ushort* Albuf, ushort* Blbuf, int r0, int n0,
                                f32x4 (&acc)[4][2])
{
    const int t  = threadIdx.x;
    const int w  = t >> 6, l = t & 63;
    const int lr = l & 15, lg = l >> 4;
    const int wr = w >> 2, wc = w & 3;       // 2x4 grid of 64x32 quadrants
    const int srow = t >> 3;                 // 0..63
    const int gch  = (t & 7) ^ (srow & 7);

    for (int kt = 0; kt < K; kt += 64) {
        __syncthreads();
        #pragma unroll
        for (int c = 0; c < 2; ++c) {
            gload_lds16(&A[(size_t)(r0 + c * 64 + srow) * K + kt + gch * 8],
                        (char*)Albuf + c * 8192 + t * 16);
            gload_lds16(&W[(size_t)(n0 + c * 64 + srow) * K + kt + gch * 8],
                        (char*)Blbuf + c * 8192 + t * 16);
        }
        __syncthreads();

        #pragma unroll
        for (int ks = 0; ks < 2; ++ks) {
            s16x8 af[4], bf[2];
            #pragma unroll
            for (int mf = 0; mf < 4; ++mf) {
                const int row = wr * 64 + mf * 16 + lr;
                const int ch  = (ks * 4 + lg) ^ (row & 7);
                af[mf] = *reinterpret_cast<const s16x8*>((const char*)Albuf + row * 128 + ch * 16);
            }
            #pragma unroll
            for (int nf = 0; nf < 2; ++nf) {
                const int row = wc * 32 + nf * 16 + lr;
                const int ch  = (ks * 4 + lg) ^ (row & 7);
                bf[nf] = *reinterpret_cast<const s16x8*>((const char*)Blbuf + row * 128 + ch * 16);
            }
            #pragma unroll
            for (int mf = 0; mf < 4; ++mf)
                #pragma unroll
                for (int nf = 0; nf < 2; ++nf)
                    acc[mf][nf] = mfma16(af[mf], bf[nf], acc[mf][nf]);
        }
    }
}

// ---------------------------------------------------------------------------
// fp32-A variant (proj), R16 form: A loaded fp32 -> regs -> cvt_pk_bf16 ->
// swizzled ds_write_b128 (write slot ci^(row&7) == read slot involution).
// W keeps the global_load_lds direct path. PROVEN at 132.8 us total.
// ---------------------------------------------------------------------------
__device__ inline void mm_core2_f32A(const float* __restrict__ A, const ushort* __restrict__ W,
                                     ushort* Albuf, ushort* Blbuf, int r0, int n0,
                                     f32x4 (&acc)[4][2])
{
    const int t  = threadIdx.x;
    const int w  = t >> 6, l = t & 63;
    const int lr = l & 15, lg = l >> 4;
    const int wr = w >> 2, wc = w & 3;
    const int srow = t >> 3;                 // 0..63 (W staging rows)
    const int gch  = (t & 7) ^ (srow & 7);
    const int arow = t >> 2;                 // 0..127 (A staging row)
    const int ac0  = (t & 3) * 2;            // this thread's first 8-col chunk
    char* aldst = (char*)Albuf + arow * 128;
    const int aslot0 = (ac0     ^ (arow & 7)) * 16;
    const int aslot1 = ((ac0+1) ^ (arow & 7)) * 16;

    for (int kt = 0; kt < K; kt += 64) {
        // issue fp32 A loads (drained at the barrier below — R16 behavior)
        const float* ap = &A[(size_t)(r0 + arow) * K + kt + ac0 * 8];
        const float4 a0 = *reinterpret_cast<const float4*>(ap);
        const float4 a1 = *reinterpret_cast<const float4*>(ap + 4);
        const float4 a2 = *reinterpret_cast<const float4*>(ap + 8);
        const float4 a3 = *reinterpret_cast<const float4*>(ap + 12);

        __syncthreads();                     // prev K-step's readers done
        #pragma unroll
        for (int c = 0; c < 2; ++c)
            gload_lds16(&W[(size_t)(n0 + c * 64 + srow) * K + kt + gch * 8],
                        (char*)Blbuf + c * 8192 + t * 16);
        {
            u32x4 q0 = {cvtpk_bf16(a0.x,a0.y), cvtpk_bf16(a0.z,a0.w),
                        cvtpk_bf16(a1.x,a1.y), cvtpk_bf16(a1.z,a1.w)};
            u32x4 q1 = {cvtpk_bf16(a2.x,a2.y), cvtpk_bf16(a2.z,a2.w),
                        cvtpk_bf16(a3.x,a3.y), cvtpk_bf16(a3.z,a3.w)};
            *reinterpret_cast<u32x4*>(aldst + aslot0) = q0;
            *reinterpret_cast<u32x4*>(aldst + aslot1) = q1;
        }
        __syncthreads();                     // staging visible (vm+lgkm drained)

        #pragma unroll
        for (int ks = 0; ks < 2; ++ks) {
            s16x8 af[4], bf[2];
            #pragma unroll
            for (int mf = 0; mf < 4; ++mf) {
                const int row = wr * 64 + mf * 16 + lr;
                const int ch  = (ks * 4 + lg) ^ (row & 7);
                af[mf] = *reinterpret_cast<const s16x8*>((const char*)Albuf + row * 128 + ch * 16);
            }
            #pragma unroll
            for (int nf = 0; nf < 2; ++nf) {
                const int row = wc * 32 + nf * 16 + lr;
                const int ch  = (ks * 4 + lg) ^ (row & 7);
                bf[nf] = *reinterpret_cast<const s16x8*>((const char*)Blbuf + row * 128 + ch * 16);
            }
            #pragma unroll
            for (int mf = 0; mf < 4; ++mf)
                #pragma unroll
                for (int nf = 0; nf < 2; ++nf)
                    acc[mf][nf] = mfma16(af[mf], bf[nf], acc[mf][nf]);
        }
    }
}

__global__ __launch_bounds__(512)
void proj_gemm(const float* __restrict__ qa, const float* __restrict__ ka,
               const float* __restrict__ va,
               const ushort* __restrict__ wq, const ushort* __restrict__ wk,
               const ushort* __restrict__ wv,
               const float* __restrict__ bq, const float* __restrict__ bk,
               const float* __restrict__ bv,
               ushort* __restrict__ qd, ushort* __restrict__ kd, ushort* __restrict__ vtd)
{
    __shared__ ushort Albuf[128 * 64];
    __shared__ ushort Blbuf[128 * 64];
    const int z = blockIdx.z;
    const float*  A    = (z == 0) ? qa : (z == 1) ? ka : va;
    const ushort* W    = (z == 0) ? wq : (z == 1) ? wk : wv;
    const float*  bias = (z == 0) ? bq : (z == 1) ? bk : bv;
    const int r0 = blockIdx.x * 128, n0 = blockIdx.y * 128;

    f32x4 acc[4][2] = {};
    mm_core2_f32A(A, W, Albuf, Blbuf, r0, n0, acc);

    const int t = threadIdx.x, w = t >> 6, l = t & 63, lr = l & 15, lg = l >> 4;
    const int wr = w >> 2, wc = w & 3;
    #pragma unroll
    for (int mf = 0; mf < 4; ++mf) {
        #pragma unroll
        for (int nf2 = 0; nf2 < 2; ++nf2) {
            const int n = n0 + wc * 32 + nf2 * 16 + lr;
            const int h = n >> 6, e = n & 63;
            const float bb = bias[n];
            #pragma unroll
            for (int rg = 0; rg < 4; ++rg) {
                const int r = r0 + wr * 64 + mf * 16 + lg * 4 + rg;
                const int i = r >> 1, m = r & 1;
                const ushort val = f2bf(acc[mf][nf2][rg] + bb);
                if (z < 2) {
                    ushort* dst = (z == 0) ? qd : kd;
                    dst[(((size_t)(h * B + m)) * S + i) * E + e] = val;
                } else {
                    vtd[(((size_t)(h * B + m)) * E + e) * S + i] = val;
                }
            }
        }
    }
}

__global__ __launch_bounds__(512)
void out_gemm(const ushort* __restrict__ A, const ushort* __restrict__ W,
              const float* __restrict__ bias, float* __restrict__ Cout)
{
    __shared__ ushort Albuf[128 * 64];
    __shared__ ushort Blbuf[128 * 64];
    const int r0 = blockIdx.x * 128, n0 = blockIdx.y * 128;

    f32x4 acc[4][2] = {};
    mm_core2(A, W, Albuf, Blbuf, r0, n0, acc);

    const int t = threadIdx.x, w = t >> 6, l = t & 63, lr = l & 15, lg = l >> 4;
    const int wr = w >> 2, wc = w & 3;
    #pragma unroll
    for (int mf = 0; mf < 4; ++mf) {
        #pragma unroll
        for (int nf2 = 0; nf2 < 2; ++nf2) {
            const int n = n0 + wc * 32 + nf2 * 16 + lr;
            const float bb = bias[n];
            #pragma unroll
            for (int rg = 0; rg < 4; ++rg) {
                const int r = r0 + wr * 64 + mf * 16 + lg * 4 + rg;
                Cout[(size_t)r * D + n] = acc[mf][nf2][rg] + bb;
            }
        }
    }
}

// ---------------------------------------------------------------------------
// prescan: fu[m] = min{j : key_mask[j,m]==0} (else S); kmf = mask * KMB2
// ---------------------------------------------------------------------------
__global__ __launch_bounds__(256)
void prescan_kernel(const int* __restrict__ km, int* __restrict__ fu,
                    float* __restrict__ kmf)
{
    __shared__ int red[256];
    const int m = blockIdx.x, t = threadIdx.x;
    int best = S;
    for (int j = t; j < S; j += 256) {
        const int v = km[(size_t)j * B + m];
        kmf[(size_t)m * S + j] = v ? KMB2 : 0.0f;
        if (v == 0) best = min(best, j);
    }
    red[t] = best;
    __syncthreads();
    for (int s = 128; s > 0; s >>= 1) {
        if (t < s) red[t] = min(red[t], red[t + s]);
        __syncthreads();
    }
    if (t == 0) fu[m] = red[0];
}

__device__ inline int nseg_of(int t)  { return (t == 0 || t >= 17) ? 2 : 1; }
__device__ inline int segoff_of(int t){ return (t == 0) ? 0 : (t <= 16 ? t + 1 : 2 * t - 16); }

// ---------------------------------------------------------------------------
// Balanced MFMA flash attention (exp2 domain), swapped QK^T, 2-phase prefetch,
// T1 XCD remap + T5 setprio, direct single-segment write — proven.
// ---------------------------------------------------------------------------
__global__ __launch_bounds__(256)
void attn_seg(const ushort* __restrict__ q, const ushort* __restrict__ k,
              const ushort* __restrict__ vt, const int* __restrict__ fu,
              const float* __restrict__ kmf,
              float* __restrict__ part_O, float* __restrict__ part_ml,
              ushort* __restrict__ a_ws)
{
    // T1 remap: 1536 blocks = 8 XCDs x 192; XCD c gets hm in [4c, 4c+4)
    const int lin = blockIdx.x + SEGS_PER_HM * (blockIdx.y + B * blockIdx.z);
    const int nf  = (lin & 7) * 192 + (lin >> 3);
    const int s   = SEG_ORDER[nf % SEGS_PER_HM];
    const int m   = (nf / SEGS_PER_HM) % B;
    const int h   = nf / (SEGS_PER_HM * B);
    int t, kk;
    if (s < 2)       { t = 0;               kk = s; }
    else if (s < 18) { t = s - 1;           kk = 0; }
    else             { t = 17 + ((s - 18) >> 1); kk = (s - 18) & 1; }
    const int i0 = t * 64;
    const int hm = h * B + m;
    const int seg = hm * SEGS_PER_HM + s;

    const int ns = nseg_of(t);
    const int h1 = (t == 0) ? 16 : ((t + 2) >> 1);
    const int jendT = (fu[m] <= i0) ? (t + 1) : 32;
    const int lo = (ns == 2 && kk == 1) ? h1 : 0;
    const int hi = (ns == 2 && kk == 0) ? min(h1, jendT) : jendT;

    const ushort* Qb  = q  + (size_t)hm * S * E;
    const ushort* Kb  = k  + (size_t)hm * S * E;
    const ushort* Vtb = vt + (size_t)hm * E * S;
    const float*  kmfm = kmf + (size_t)m * S;

    __shared__ ushort Ks[2][KVB * 64];
    __shared__ ushort Vts[2][E * 64];
    __shared__ ushort Pw[4][16 * 64];

    const int tid = threadIdx.x;
    const int wv  = tid >> 6;
    const int l   = tid & 63;
    const int lg  = l >> 4;
    const int lcc = l & 15;
    const int a7  = lcc & 7;
    const int gi  = i0 + wv * 16 + lcc;

    const int srow = tid >> 3;
    const int sch  = (tid & 7) ^ (srow & 7);

    s16x8 qf0, qf1;
    {
        const ushort* qp = &Qb[(size_t)gi * E + lg * 8];
        qf0 = *reinterpret_cast<const s16x8*>(qp);
        qf1 = *reinterpret_cast<const s16x8*>(qp + 32);
    }

    float m_run = -INFINITY, l_run = 0.0f;
    f32x4 oacc[4] = {};

    auto STAGE = [&](int buf, int tj) {
        const int j0 = tj * 64;
        gload_lds16(&Kb[(size_t)(j0 + srow) * E + sch * 8],
                    (char*)&Ks[buf][0] + tid * 16);
        gload_lds16(&Kb[(size_t)(j0 + 32 + srow) * E + sch * 8],
                    (char*)&Ks[buf][0] + 4096 + tid * 16);
        gload_lds16(&Vtb[(size_t)srow * S + j0 + sch * 8],
                    (char*)&Vts[buf][0] + tid * 16);
        gload_lds16(&Vtb[(size_t)(32 + srow) * S + j0 + sch * 8],
                    (char*)&Vts[buf][0] + 4096 + tid * 16);
    };

    STAGE(0, lo);
    __syncthreads();
    int cur = 0;

    for (int tj = lo; tj < hi; ++tj) {
        const int j0 = tj * 64;
        if (tj + 1 < hi) STAGE(cur ^ 1, tj + 1);

        float4 km4[4];
        #pragma unroll
        for (int jt = 0; jt < 4; ++jt)
            km4[jt] = *reinterpret_cast<const float4*>(&kmfm[j0 + jt * 16 + lg * 4]);

        // ---- S^T = K . Q^T  (T5 boost)
        f32x4 sacc[4];
        __builtin_amdgcn_s_setprio(1);
        #pragma unroll
        for (int jt = 0; jt < 4; ++jt) {
            const char* kb = (const char*)&Ks[cur][0] + (jt * 16 + lcc) * 128;
            s16x8 kf0 = *reinterpret_cast<const s16x8*>(kb + (lg ^ a7) * 16);
            s16x8 kf1 = *reinterpret_cast<const s16x8*>(kb + ((lg ^ a7) ^ 4) * 16);
            f32x4 a = {};
            a = mfma16(kf0, qf0, a);
            a = mfma16(kf1, qf1, a);
            sacc[jt] = a;
        }
        __builtin_amdgcn_s_setprio(0);

        // ---- scale + masks in exp2 domain
        if (j0 >= i0) {
            #pragma unroll
            for (int jt = 0; jt < 4; ++jt) {
                const int jmi = j0 + jt * 16 + lg * 4 - gi;
                #pragma unroll
                for (int r = 0; r < 4; ++r) {
                    float sc = fmaf(sacc[jt][r], QSCL, -((const float*)&km4[jt])[r]);
                    sc -= (jmi + r > 0) ? KMB2 : 0.0f;
                    sacc[jt][r] = sc;
                }
            }
        } else {
            #pragma unroll
            for (int jt = 0; jt < 4; ++jt)
                #pragma unroll
                for (int r = 0; r < 4; ++r)
                    sacc[jt][r] = fmaf(sacc[jt][r], QSCL, -((const float*)&km4[jt])[r]);
        }

        // ---- online softmax, defer-rescale
        float mm = -INFINITY;
        #pragma unroll
        for (int jt = 0; jt < 4; ++jt)
            #pragma unroll
            for (int r = 0; r < 4; ++r) mm = fmaxf(mm, sacc[jt][r]);
        mm = fmaxf(mm, __shfl_xor(mm, 16));
        mm = fmaxf(mm, __shfl_xor(mm, 32));

        if (!__all(mm <= m_run)) {
            const float m_new = fmaxf(m_run, mm);
            const float scale = fexp2(m_run - m_new);
            m_run = m_new;
            l_run *= scale;
            float scr[4];
            #pragma unroll
            for (int r = 0; r < 4; ++r)
                scr[r] = __shfl(scale, (l & 48) | (lg * 4 + r));
            #pragma unroll
            for (int et = 0; et < 4; ++et)
                #pragma unroll
                for (int r = 0; r < 4; ++r) oacc[et][r] *= scr[r];
        }

        float psum = 0.0f;
        #pragma unroll
        for (int jt = 0; jt < 4; ++jt) {
            const float p0 = fexp2(sacc[jt][0] - m_run);
            const float p1 = fexp2(sacc[jt][1] - m_run);
            const float p2 = fexp2(sacc[jt][2] - m_run);
            const float p3 = fexp2(sacc[jt][3] - m_run);
            psum += (p0 + p1) + (p2 + p3);
            const u32 w0 = cvtpk_bf16(p0, p1);
            const u32 w1 = cvtpk_bf16(p2, p3);
            const int pby = lcc * 128 + (((jt * 2 + (lg >> 1)) ^ a7) << 4) + ((lg & 1) << 3);
            *reinterpret_cast<u32x2*>((char*)&Pw[wv][0] + pby) = (u32x2){w0, w1};
        }
        psum += __shfl_xor(psum, 16);
        psum += __shfl_xor(psum, 32);
        l_run += psum;

        // ---- PV: A = P (per-wave LDS), B = V^T  (T5 boost)
        {
            const char* pb = (const char*)&Pw[wv][0] + lcc * 128;
            __builtin_amdgcn_s_setprio(1);
            s16x8 pf0 = *reinterpret_cast<const s16x8*>(pb + (lg ^ a7) * 16);
            s16x8 pf1 = *reinterpret_cast<const s16x8*>(pb + ((lg ^ a7) ^ 4) * 16);
            #pragma unroll
            for (int et = 0; et < 4; ++et) {
                const char* vb = (const char*)&Vts[cur][0] + (et * 16 + lcc) * 128;
                s16x8 vf0 = *reinterpret_cast<const s16x8*>(vb + (lg ^ a7) * 16);
                s16x8 vf1 = *reinterpret_cast<const s16x8*>(vb + ((lg ^ a7) ^ 4) * 16);
                oacc[et] = mfma16(pf0, vf0, oacc[et]);
                oacc[et] = mfma16(pf1, vf1, oacc[et]);
            }
            __builtin_amdgcn_s_setprio(0);
        }

        __syncthreads();
        cur ^= 1;
    }

    if (ns == 1) {
        // single segment: normalize and emit bf16 directly
        const float inv = 1.0f / l_run;
        float linv4[4];
        #pragma unroll
        for (int r = 0; r < 4; ++r)
            linv4[r] = __shfl(inv, (l & 48) | (lg * 4 + r));
        #pragma unroll
        for (int et = 0; et < 4; ++et) {
            #pragma unroll
            for (int r = 0; r < 4; ++r) {
                const int gi2 = i0 + wv * 16 + lg * 4 + r;
                a_ws[((size_t)gi2 * B + m) * D + h * E + et * 16 + lcc] =
                    f2bf(oacc[et][r] * linv4[r]);
            }
        }
    } else {
        #pragma unroll
        for (int et = 0; et < 4; ++et)
            #pragma unroll
            for (int r = 0; r < 4; ++r)
                part_O[((size_t)seg * 64 + wv * 16 + lg * 4 + r) * 64 + et * 16 + lcc] = oacc[et][r];
        if (lg == 0) {
            part_ml[((size_t)seg * 64 + wv * 16 + lcc) * 2]     = m_run;
            part_ml[((size_t)seg * 64 + wv * 16 + lcc) * 2 + 1] = l_run;
        }
    }
}

// ---------------------------------------------------------------------------
// combine: merge the 2-segment q-tiles only (t=0, 17..31)
// ---------------------------------------------------------------------------
__global__ __launch_bounds__(256)
void attn_combine(const float* __restrict__ part_O, const float* __restrict__ part_ml,
                  ushort* __restrict__ a_ws)
{
    const int t = (blockIdx.x == 0) ? 0 : (16 + blockIdx.x);   // 0, 17..31
    const int m = blockIdx.y, h = blockIdx.z;
    const int hm = h * B + m;
    const int seg0 = hm * SEGS_PER_HM + segoff_of(t);

    const int tid = threadIdx.x;
    const int row = tid >> 2;
    const int e0  = (tid & 3) * 16;
    const int gi  = t * 64 + row;

    const size_t r0 = (size_t)seg0 * 64 + row;
    const size_t r1 = ((size_t)(seg0 + 1)) * 64 + row;
    const float m0 = part_ml[r0 * 2], l0 = part_ml[r0 * 2 + 1];
    const float m1 = part_ml[r1 * 2], l1 = part_ml[r1 * 2 + 1];
    const float ms = fmaxf(m0, m1);
    const float w0 = fexp2(m0 - ms);
    const float w1 = fexp2(m1 - ms);
    const float linv = 1.0f / (l0 * w0 + l1 * w1);

    ushort* dst = a_ws + ((size_t)gi * B + m) * D + h * E + e0;
    #pragma unroll
    for (int c = 0; c < 4; ++c) {
        float4 o0 = *reinterpret_cast<const float4*>(&part_O[r0 * 64 + e0 + c * 4]);
        float4 o1 = *reinterpret_cast<const float4*>(&part_O[r1 * 64 + e0 + c * 4]);
        float ov[4];
        ov[0] = o0.x * w0 + o1.x * w1;
        ov[1] = o0.y * w0 + o1.y * w1;
        ov[2] = o0.z * w0 + o1.z * w1;
        ov[3] = o0.w * w0 + o1.w * w1;
        dst[c * 4 + 0] = f2bf(ov[0] * linv);
        dst[c * 4 + 1] = f2bf(ov[1] * linv);
        dst[c * 4 + 2] = f2bf(ov[2] * linv);
        dst[c * 4 + 3] = f2bf(ov[3] * linv);
    }
}

} // anonymous namespace

extern "C" void kernel_launch(void* const* d_in, const int* in_sizes, int n_in,
                              void* d_out, int out_size, void* d_ws, size_t ws_size,
                              hipStream_t stream)
{
    const float* query = (const float*)d_in[0];
    const float* key   = (const float*)d_in[1];
    const float* value = (const float*)d_in[2];
    const int*   kmask = (const int*)  d_in[3];
    const float* Wq    = (const float*)d_in[4];
    const float* bq    = (const float*)d_in[5];
    const float* Wk    = (const float*)d_in[6];
    const float* bk    = (const float*)d_in[7];
    const float* Wv    = (const float*)d_in[8];
    const float* bv    = (const float*)d_in[9];
    const float* Wo    = (const float*)d_in[10];
    const float* bo    = (const float*)d_in[11];
    float* out = (float*)d_out;

    const size_t act = (size_t)RM * D;
    const size_t wsz = (size_t)D * D;
    ushort* wob  = (ushort*)d_ws;
    ushort* wqb  = wob + wsz;
    ushort* wkb  = wqb + wsz;
    ushort* wvb  = wkb + wsz;
    ushort* qa   = wvb + wsz;              // region unused by GEMMs;
    ushort* ka   = qa + act;               // reused for attn partials only
    ushort* va   = ka + act;
    ushort* q_ws = va + act;
    ushort* k_ws = q_ws + act;
    ushort* vt_ws= k_ws + act;
    ushort* a_ws = vt_ws + act;
    float* part_O  = (float*)qa;           // 1536*64*64 f32 == 3*act ushorts
    float* part_ml = (float*)wqb;          // 786 KB < 2 MB
    int*   fu      = (int*)wkb;            // 16 B
    float* kmf     = (float*)wkb + 8;      // S*B f32 = 16 KB < 2 MB

    cvt4_kernel<<<dim3(wsz / 8 / 256, 4), 256, 0, stream>>>(Wq, Wk, Wv, Wo, wqb, wkb, wvb, wob);

    proj_gemm<<<dim3(RM / 128, D / 128, 3), 512, 0, stream>>>(
        query, key, value, wqb, wkb, wvb, bq, bk, bv, q_ws, k_ws, vt_ws);

    prescan_kernel<<<dim3(B), 256, 0, stream>>>(kmask, fu, kmf);

    attn_seg<<<dim3(SEGS_PER_HM, B, H), 256, 0, stream>>>(
        q_ws, k_ws, vt_ws, fu, kmf, part_O, part_ml, a_ws);

    attn_combine<<<dim3(16, B, H), 256, 0, stream>>>(part_O, part_ml, a_ws);

    out_gemm<<<dim3(RM / 128, D / 128), 512, 0, stream>>>(a_ws, wob, bo, out);
}